// Round 15
// baseline (259.051 us; speedup 1.0000x reference)
//
#include <hip/hip_runtime.h>
#include <hip/hip_bf16.h>

#define EMBED 768
#define HEADS 12
#define HD 64
#define BATCH 4
#define SEQ 2048
#define M_TOK (BATCH*SEQ)   // 8192
#define N_QKV (3*EMBED)     // 2304
#define SL2E 0.18033688011112042f   // (1/8) * log2(e)

typedef short bf8 __attribute__((ext_vector_type(8)));
typedef float f4  __attribute__((ext_vector_type(4)));
typedef float f16v __attribute__((ext_vector_type(16)));
typedef unsigned short us8 __attribute__((ext_vector_type(8)));
typedef unsigned int u32x4 __attribute__((ext_vector_type(4)));

static __device__ inline unsigned short f2bf(float f) {
    unsigned int x = __float_as_uint(f);
    unsigned int r = (x + 0x7fffu + ((x >> 16) & 1u)) >> 16;   // RNE
    return (unsigned short)r;
}

// pack two fp32 -> packed bf16x2
static __device__ inline unsigned int pack2bf(float a, float b) {
#if defined(__has_builtin)
#if __has_builtin(__builtin_amdgcn_cvt_pk_bf16_f32)
    auto r = __builtin_amdgcn_cvt_pk_bf16_f32(a, b);
    return __builtin_bit_cast(unsigned int, r);
#else
    unsigned int ua = (__float_as_uint(a) + 0x8000u) >> 16;
    unsigned int ub = (__float_as_uint(b) + 0x8000u) & 0xffff0000u;
    return ua | ub;
#endif
#else
    unsigned int ua = (__float_as_uint(a) + 0x8000u) >> 16;
    unsigned int ub = (__float_as_uint(b) + 0x8000u) & 0xffff0000u;
    return ua | ub;
#endif
}

#define GLD_LDS(gp, lp) __builtin_amdgcn_global_load_lds( \
    (const __attribute__((address_space(1))) void*)(gp),  \
    (__attribute__((address_space(3))) void*)(lp), 16, 0, 0)

// ---------------- fused prep: cvt + 2 transposes + bias scale in ONE launch ----------
// r6-verified. UNCHANGED.
#define CVT_BLOCKS  ((M_TOK * EMBED) / 1024)                 // 6144
#define TQ_BLOCKS   ((N_QKV / 32) * (EMBED / 32))            // 72*24 = 1728
#define TP_BLOCKS   ((EMBED / 32) * (EMBED / 32))            // 24*24 = 576
#define SB_BLOCKS   9
#define PREP_BLOCKS (CVT_BLOCKS + TQ_BLOCKS + TP_BLOCKS + SB_BLOCKS)

static __device__ inline void transpose_tile(const float* __restrict__ in,
                                             unsigned short* __restrict__ out,
                                             int R, int C, float scale, int nlim,
                                             int c0, int r0, int tx, int ty,
                                             float (*tile)[33]) {
    for (int i = 0; i < 32; i += 8)
        tile[ty + i][tx] = in[(size_t)(r0 + ty + i) * C + c0 + tx];
    __syncthreads();
    for (int i = 0; i < 32; i += 8) {
        int orow = c0 + ty + i;
        float s = (orow < nlim) ? scale : 1.0f;
        out[(size_t)orow * R + r0 + tx] = f2bf(tile[tx][ty + i] * s);
    }
}

__global__ __launch_bounds__(256) void prep_fused(
    const float* __restrict__ x,      unsigned short* __restrict__ xbf,
    const float* __restrict__ w_qkv,  unsigned short* __restrict__ wqkvT,
    const float* __restrict__ w_proj, unsigned short* __restrict__ wprojT,
    const float* __restrict__ b_qkv,  float* __restrict__ bqkv_s) {
    __shared__ float tile[32][33];
    int bid = blockIdx.x, tid = threadIdx.x;
    if (bid < CVT_BLOCKS) {
        int i = (bid * 256 + tid) * 4;
        float4 v = *reinterpret_cast<const float4*>(x + i);
        ushort4 o;
        o.x = f2bf(v.x); o.y = f2bf(v.y); o.z = f2bf(v.z); o.w = f2bf(v.w);
        *reinterpret_cast<ushort4*>(xbf + i) = o;
    } else if (bid < CVT_BLOCKS + TQ_BLOCKS) {
        int t = bid - CVT_BLOCKS;
        int bx = t % (N_QKV / 32), by = t / (N_QKV / 32);
        transpose_tile(w_qkv, wqkvT, EMBED, N_QKV, SL2E, 768,
                       bx * 32, by * 32, tid & 31, tid >> 5, tile);
    } else if (bid < CVT_BLOCKS + TQ_BLOCKS + TP_BLOCKS) {
        int t = bid - CVT_BLOCKS - TQ_BLOCKS;
        int bx = t % (EMBED / 32), by = t / (EMBED / 32);
        transpose_tile(w_proj, wprojT, EMBED, EMBED, 1.0f, 0,
                       bx * 32, by * 32, tid & 31, tid >> 5, tile);
    } else {
        int i = (bid - CVT_BLOCKS - TQ_BLOCKS - TP_BLOCKS) * 256 + tid;
        if (i < N_QKV) bqkv_s[i] = b_qkv[i] * (i < 768 ? SL2E : 1.0f);
    }
}

// ------------- 256^2 bf16 GEMM (r12-verified-correct) — used for gemm0 ONLY -------------
// Round-22 bisection: r12 switched BOTH gemms to 256^2 and regressed +42us,
// but the per-GEMM split was never measured. gemm0 (288 blocks, 12% tail) may
// have IMPROVED while gemm1 (96 blocks, 62% of CUs idle, 1 block/CU) was the
// catastrophe. This round: 256^2 for gemm0 only; gemm1 stays 128^2.
// Code verbatim from r12 (passed correctness, absmax 0.001953125).
template<int OUT_MODE>
__global__ __launch_bounds__(512, 2) void gemm_bf16_256(
    const unsigned short* __restrict__ A,
    const unsigned short* __restrict__ BT,
    const float* __restrict__ bias,
    void* __restrict__ Cout, int M, int N, int K)
{
    const int LDA = 32;
    __shared__ unsigned short a_lds[3][256 * 32];
    __shared__ unsigned short b_lds[3][256 * 32];
    int tid  = threadIdx.x;
    int lane = tid & 63, w = tid >> 6;
    int quad = lane >> 4, cc = lane & 15;
    int m0 = blockIdx.x * 256, n0 = blockIdx.y * 256;
    int wr = w >> 2, wc = w & 3;
    int mb = wr * 128, nb = wc * 64;
    const unsigned short* Ab = A + (size_t)m0 * K;
    const unsigned short* Bb = BT + (size_t)n0 * K;
    f4 acc[8][4] = {};
    int li0 = tid,       row0 = li0 >> 2, ch0 = li0 & 3;
    int li1 = 512 + tid, row1 = li1 >> 2, ch1 = li1 & 3;
    GLD_LDS(Ab + (size_t)row0 * K + ch0 * 8,      &a_lds[0][li0 * 8]);
    GLD_LDS(Ab + (size_t)row1 * K + ch1 * 8,      &a_lds[0][li1 * 8]);
    GLD_LDS(Bb + (size_t)row0 * K + ch0 * 8,      &b_lds[0][li0 * 8]);
    GLD_LDS(Bb + (size_t)row1 * K + ch1 * 8,      &b_lds[0][li1 * 8]);
    GLD_LDS(Ab + (size_t)row0 * K + 32 + ch0 * 8, &a_lds[1][li0 * 8]);
    GLD_LDS(Ab + (size_t)row1 * K + 32 + ch1 * 8, &a_lds[1][li1 * 8]);
    GLD_LDS(Bb + (size_t)row0 * K + 32 + ch0 * 8, &b_lds[1][li0 * 8]);
    GLD_LDS(Bb + (size_t)row1 * K + 32 + ch1 * 8, &b_lds[1][li1 * 8]);
    int cur = 0;
    for (int k0 = 0; k0 < K; k0 += 32) {
        if (k0 + 32 < K) {
            asm volatile("s_waitcnt vmcnt(4)\n\ts_barrier" ::: "memory");
        } else {
            asm volatile("s_waitcnt vmcnt(0)\n\ts_barrier" ::: "memory");
        }
        int kn = k0 + 64;
        if (kn < K) {
            int sb = cur + 2; if (sb >= 3) sb -= 3;
            GLD_LDS(Ab + (size_t)row0 * K + kn + ch0 * 8, &a_lds[sb][li0 * 8]);
            GLD_LDS(Ab + (size_t)row1 * K + kn + ch1 * 8, &a_lds[sb][li1 * 8]);
            GLD_LDS(Bb + (size_t)row0 * K + kn + ch0 * 8, &b_lds[sb][li0 * 8]);
            GLD_LDS(Bb + (size_t)row1 * K + kn + ch1 * 8, &b_lds[sb][li1 * 8]);
        }
        bf8 af[8], bfv[4];
#pragma unroll
        for (int mi = 0; mi < 8; ++mi)
            af[mi] = *reinterpret_cast<const bf8*>(&a_lds[cur][(mb + mi * 16 + cc) * LDA + quad * 8]);
#pragma unroll
        for (int ni = 0; ni < 4; ++ni)
            bfv[ni] = *reinterpret_cast<const bf8*>(&b_lds[cur][(nb + ni * 16 + cc) * LDA + quad * 8]);
#pragma unroll
        for (int mi = 0; mi < 8; ++mi)
#pragma unroll
            for (int ni = 0; ni < 4; ++ni)
                acc[mi][ni] = __builtin_amdgcn_mfma_f32_16x16x32_bf16(af[mi], bfv[ni], acc[mi][ni], 0, 0, 0);
        cur = (cur == 2) ? 0 : cur + 1;
    }
#pragma unroll
    for (int mi = 0; mi < 8; ++mi)
#pragma unroll
        for (int ni = 0; ni < 4; ++ni) {
            int gn = n0 + nb + ni * 16 + cc;
            float bv = bias[gn];
#pragma unroll
            for (int r = 0; r < 4; ++r) {
                int gm = m0 + mb + mi * 16 + quad * 4 + r;
                float v = acc[mi][ni][r] + bv;
                if (OUT_MODE == 0)
                    ((unsigned short*)Cout)[(size_t)gm * N + gn] = f2bf(v);
                else
                    ((float*)Cout)[(size_t)gm * N + gn] = v;
            }
        }
}

// ------------- 128^2 bf16 GEMM (r11/r14-verified) — used for gemm1 -------------
// Triple-buffer + counted vmcnt(4) + raw s_barrier + XCD remap. UNCHANGED.
template<int OUT_MODE>  // 0: bf16 out, 1: fp32 out
__global__ __launch_bounds__(256) void gemm_bf16(
    const unsigned short* __restrict__ A,
    const unsigned short* __restrict__ BT,
    const float* __restrict__ bias,
    void* __restrict__ Cout, int M, int N, int K)
{
    const int LDA = 32;  // unpadded: lane-linear global_load_lds dest
    __shared__ unsigned short a_lds[3][128 * 32];
    __shared__ unsigned short b_lds[3][128 * 32];
    int tid  = threadIdx.x;
    int lane = tid & 63, w = tid >> 6;
    int quad = lane >> 4, cc = lane & 15;
    int id  = blockIdx.x;
    int xcd = id & 7, j = id >> 3;
    int m0 = (xcd * 8 + (j & 7)) * 128;
    int n0 = (j >> 3) * 128;
    int wr = w >> 1, wc = w & 1;
    int mb = wr * 64, nb = wc * 64;
    const unsigned short* Ab = A + (size_t)m0 * K;
    const unsigned short* Bb = BT + (size_t)n0 * K;
    f4 acc[4][4] = {};
    int li0 = tid,       row0 = li0 >> 2, ch0 = li0 & 3;
    int li1 = 256 + tid, row1 = li1 >> 2, ch1 = li1 & 3;
    GLD_LDS(Ab + (size_t)row0 * K + ch0 * 8,      &a_lds[0][li0 * 8]);
    GLD_LDS(Bb + (size_t)row0 * K + ch0 * 8,      &b_lds[0][li0 * 8]);
    GLD_LDS(Ab + (size_t)row1 * K + ch1 * 8,      &a_lds[0][li1 * 8]);
    GLD_LDS(Bb + (size_t)row1 * K + ch1 * 8,      &b_lds[0][li1 * 8]);
    GLD_LDS(Ab + (size_t)row0 * K + 32 + ch0 * 8, &a_lds[1][li0 * 8]);
    GLD_LDS(Bb + (size_t)row0 * K + 32 + ch0 * 8, &b_lds[1][li0 * 8]);
    GLD_LDS(Ab + (size_t)row1 * K + 32 + ch1 * 8, &a_lds[1][li1 * 8]);
    GLD_LDS(Bb + (size_t)row1 * K + 32 + ch1 * 8, &b_lds[1][li1 * 8]);
    int cur = 0;
    for (int k0 = 0; k0 < K; k0 += 32) {
        if (k0 + 32 < K) {
            asm volatile("s_waitcnt vmcnt(4)\n\ts_barrier" ::: "memory");
        } else {
            asm volatile("s_waitcnt vmcnt(0)\n\ts_barrier" ::: "memory");
        }
        int kn = k0 + 64;
        if (kn < K) {
            int sb = cur + 2; if (sb >= 3) sb -= 3;
            GLD_LDS(Ab + (size_t)row0 * K + kn + ch0 * 8, &a_lds[sb][li0 * 8]);
            GLD_LDS(Bb + (size_t)row0 * K + kn + ch0 * 8, &b_lds[sb][li0 * 8]);
            GLD_LDS(Ab + (size_t)row1 * K + kn + ch1 * 8, &a_lds[sb][li1 * 8]);
            GLD_LDS(Bb + (size_t)row1 * K + kn + ch1 * 8, &b_lds[sb][li1 * 8]);
        }
        bf8 af[4], bfv[4];
        for (int mi = 0; mi < 4; ++mi)
            af[mi] = *reinterpret_cast<const bf8*>(&a_lds[cur][(mb + mi * 16 + cc) * LDA + quad * 8]);
        for (int ni = 0; ni < 4; ++ni)
            bfv[ni] = *reinterpret_cast<const bf8*>(&b_lds[cur][(nb + ni * 16 + cc) * LDA + quad * 8]);
        for (int mi = 0; mi < 4; ++mi)
            for (int ni = 0; ni < 4; ++ni)
                acc[mi][ni] = __builtin_amdgcn_mfma_f32_16x16x32_bf16(af[mi], bfv[ni], acc[mi][ni], 0, 0, 0);
        cur = (cur == 2) ? 0 : cur + 1;
    }
    for (int mi = 0; mi < 4; ++mi)
        for (int ni = 0; ni < 4; ++ni) {
            int gn = n0 + nb + ni * 16 + cc;
            float bv = bias[gn];
            for (int r = 0; r < 4; ++r) {
                int gm = m0 + mb + mi * 16 + quad * 4 + r;
                float v = acc[mi][ni][r] + bv;
                if (OUT_MODE == 0)
                    ((unsigned short*)Cout)[(size_t)gm * N + gn] = f2bf(v);
                else
                    ((float*)Cout)[(size_t)gm * N + gn] = v;
            }
        }
}

// ------- V transpose: qkv[.][1536+h*64+d] -> vt[b][h][d][t], LDS-tiled -------
__global__ __launch_bounds__(256) void vtrans(
    const unsigned short* __restrict__ qkv, unsigned short* __restrict__ vt)
{
    __shared__ unsigned short lds[64 * 72];
    int tid = threadIdx.x;
    int t0 = blockIdx.x * 64, h = blockIdx.y, b = blockIdx.z;
    for (int p = 0; p < 2; ++p) {
        int li = p * 256 + tid, row = li >> 3, col = li & 7;
        *reinterpret_cast<uint4*>(&lds[row * 72 + col * 8]) =
            *reinterpret_cast<const uint4*>(
                qkv + (size_t)(b * SEQ + t0 + row) * 2304 + 1536 + h * 64 + col * 8);
    }
    __syncthreads();
    for (int p = 0; p < 2; ++p) {
        int li = p * 256 + tid, d = li >> 3, tc = li & 7;
        us8 v;
        for (int j = 0; j < 8; ++j) v[j] = lds[(tc * 8 + j) * 72 + d];
        *reinterpret_cast<us8*>(
            vt + ((size_t)(b * HEADS + h) * 64 + d) * SEQ + t0 + tc * 8) = v;
    }
}

// ---------------- flash attention, 32x32x16 MFMA, q x key wave split ----------------
// r3-proven (92.4us band). UNCHANGED (control).
__global__ __launch_bounds__(512, 4) void attn_kernel(
    const unsigned short* __restrict__ qkv,  // [B*T][2304] bf16 (q pre-scaled)
    const unsigned short* __restrict__ vt,   // [B][H][64][T] bf16
    unsigned short* __restrict__ out)        // [B*T][768] bf16
{
    const int LDK = 72;  // 64 + 8 pad
    __shared__ unsigned short smem[18432];   // 36864 B total
    unsigned short* k0b = smem;              // buf0 K [64][72]
    unsigned short* v0b = smem + 4608;       // buf0 V
    unsigned short* k1b = smem + 9216;       // buf1 K
    unsigned short* v1b = smem + 13824;      // buf1 V
    int tid  = threadIdx.x;
    int lane = tid & 63, w = tid >> 6;       // w = 0..7
    int ln   = lane & 31, hk = lane >> 5;    // n-index / k-half within frag
    int qq   = w >> 1, kh = w & 1;           // q-quarter, key-half
    // swizzle: all 16 q-tiles of one (b,h) share id%8 -> same XCD L2
    int id  = blockIdx.x;
    int sub = id >> 3, rem = id & 7;
    int g   = (sub >> 4) * 8 + rem;          // 0..47
    int qt  = sub & 15;
    int b   = g / HEADS, h = g % HEADS;
    int q0  = qt * 128;

    // Q resident as 32x32 B-fragments: B[n=ln -> q][k=kb*16+hk*8+j]
    bf8 qf[4];
    {
        const unsigned short* qp =
            qkv + (size_t)(b * SEQ + q0 + qq * 32 + ln) * 2304 + h * 64 + hk * 8;
        qf[0] = *reinterpret_cast<const bf8*>(qp);
        qf[1] = *reinterpret_cast<const bf8*>(qp + 16);
        qf[2] = *reinterpret_cast<const bf8*>(qp + 32);
        qf[3] = *reinterpret_cast<const bf8*>(qp + 48);
    }
    f16v acc[2] = {};            // [db=d/32]; C: col d = db*32+ln, row q = (reg&3)+8*(reg>>2)+4*hk
    float lsum = 0.f;
    const unsigned short* kbase = qkv + (size_t)b * SEQ * 2304 + 768 + h * 64;
    const unsigned short* vbase = vt + (size_t)(b * HEADS + h) * 64 * SEQ;

    // staging: 512 threads cover 64 rows x 8 chunks once each for K and V
    int srow = tid >> 3, scol = tid & 7;
    const unsigned short* kp = kbase + (size_t)srow * 2304 + scol * 8;
    const unsigned short* vp = vbase + (size_t)srow * SEQ + scol * 8;
    int soff = srow * LDK + scol * 8;

    // prologue: stage tile 0 directly, then prefetch tile 1 into registers
    uint4 kr = *reinterpret_cast<const uint4*>(kp);
    uint4 vr = *reinterpret_cast<const uint4*>(vp);
    *reinterpret_cast<uint4*>(k0b + soff) = kr;
    *reinterpret_cast<uint4*>(v0b + soff) = vr;
    kr = *reinterpret_cast<const uint4*>(kp + (size_t)64 * 2304);
    vr = *reinterpret_cast<const uint4*>(vp + 64);

    const int krow  = (kh * 32 + ln) * LDK + hk * 8;        // K frag base
    const int vrow0 = ln * LDK + kh * 32 + hk * 8;          // V frag base db=0
    const int vrow1 = (32 + ln) * LDK + kh * 32 + hk * 8;   // V frag base db=1

    auto step = [&](const unsigned short* kc, const unsigned short* vc,
                    unsigned short* ko, unsigned short* vo, int kt) {
        __syncthreads();   // buf(kc,vc) visible; prior readers of (ko,vo) drained;
                           // outstanding loads are 1 full phase old -> drain ~free
        // stage tile kt+64 into the other buffer NOW, then issue kt+128 loads:
        // the loads get the whole compute phase below to land before next barrier.
        if (kt + 64 < SEQ) {
            *reinterpret_cast<uint4*>(ko + soff) = kr;
            *reinterpret_cast<uint4*>(vo + soff) = vr;
            if (kt + 128 < SEQ) {
                kr = *reinterpret_cast<const uint4*>(kp + (size_t)(kt + 128) * 2304);
                vr = *reinterpret_cast<const uint4*>(vp + (kt + 128));
            }
        }
        // S^T = K·Q^T over this wave's 32-key half. C: row=key, col=q
        bf8 a0 = *reinterpret_cast<const bf8*>(&kc[krow]);
        bf8 a1 = *reinterpret_cast<const bf8*>(&kc[krow + 16]);
        bf8 a2 = *reinterpret_cast<const bf8*>(&kc[krow + 32]);
        bf8 a3 = *reinterpret_cast<const bf8*>(&kc[krow + 48]);
        f16v z = {};
        z = __builtin_amdgcn_mfma_f32_32x32x16_bf16(a0, qf[0], z, 0, 0, 0);
        z = __builtin_amdgcn_mfma_f32_32x32x16_bf16(a1, qf[1], z, 0, 0, 0);
        z = __builtin_amdgcn_mfma_f32_32x32x16_bf16(a2, qf[2], z, 0, 0, 0);
        z = __builtin_amdgcn_mfma_f32_32x32x16_bf16(a3, qf[3], z, 0, 0, 0);
        // V frags issued now -> DS latency hides under exp2/pack VALU
        bf8 v00 = *reinterpret_cast<const bf8*>(&vc[vrow0]);
        bf8 v01 = *reinterpret_cast<const bf8*>(&vc[vrow0 + 16]);
        bf8 v10 = *reinterpret_cast<const bf8*>(&vc[vrow1]);
        bf8 v11 = *reinterpret_cast<const bf8*>(&vc[vrow1 + 16]);
        // exp2 + in-register P. z reg r holds key (r&3)+8*(r>>2)+4*hk (+kh*32)
        float e[16];
#pragma unroll
        for (int r = 0; r < 16; ++r) e[r] = exp2f(z[r]);
#pragma unroll
        for (int gg = 0; gg < 4; ++gg)
            lsum += (e[4 * gg] + e[4 * gg + 1]) + (e[4 * gg + 2] + e[4 * gg + 3]);
        unsigned int w0 = pack2bf(e[0],  e[1]),  w1 = pack2bf(e[2],  e[3]);
        unsigned int w2 = pack2bf(e[4],  e[5]),  w3 = pack2bf(e[6],  e[7]);
        unsigned int w4 = pack2bf(e[8],  e[9]),  w5 = pack2bf(e[10], e[11]);
        unsigned int w6 = pack2bf(e[12], e[13]), w7 = pack2bf(e[14], e[15]);
        // v_permlane32_swap: hi-half(op0) <-> lo-half(op1)  (T12 recipe order).
        // After swap(w0,w2): w0 = A-word0 {k0,k1|k8,k9}, w2 = A-word2 {k4,k5|k12,k13}
        asm("v_permlane32_swap_b32 %0, %1" : "+v"(w0), "+v"(w2));
        asm("v_permlane32_swap_b32 %0, %1" : "+v"(w1), "+v"(w3));
        asm("v_permlane32_swap_b32 %0, %1" : "+v"(w4), "+v"(w6));
        asm("v_permlane32_swap_b32 %0, %1" : "+v"(w5), "+v"(w7));
        u32x4 pu0 = {w0, w1, w2, w3};   // A[m=q=ln][k = hk*8 + 0..7]   (keys kh*32+0..15)
        u32x4 pu1 = {w4, w5, w6, w7};   // keys kh*32+16..31
        bf8 pa0 = __builtin_bit_cast(bf8, pu0);
        bf8 pa1 = __builtin_bit_cast(bf8, pu1);
        // O += P·V over this wave's key-half
        acc[0] = __builtin_amdgcn_mfma_f32_32x32x16_bf16(pa0, v00, acc[0], 0, 0, 0);
        acc[0] = __builtin_amdgcn_mfma_f32_32x32x16_bf16(pa1, v01, acc[0], 0, 0, 0);
        acc[1] = __builtin_amdgcn_mfma_f32_32x32x16_bf16(pa0, v10, acc[1], 0, 0, 0);
        acc[1] = __builtin_amdgcn_mfma_f32_32x32x16_bf16(pa1, v11, acc[1], 0, 0, 0);
    };

    for (int kt = 0; kt < SEQ; kt += 128) {
        step(k0b, v0b, k1b, v1b, kt);
        step(k1b, v1b, k0b, v0b, kt + 64);
    }

    // combine the two key-halves (wave pairs w, w^1) through reused LDS
    lsum += __shfl_xor(lsum, 32);   // full key-half sum for q = qq*32+ln
    __syncthreads();                // everyone done with k/v before reuse
    float* olds  = reinterpret_cast<float*>(smem);   // 8192 floats = 32768 B
    float* l_lds = olds + 8192;                      // 128 floats
    if (kh) {
        for (int db = 0; db < 2; ++db)
            for (int gg = 0; gg < 4; ++gg) {
                float4 vv = { acc[db][4 * gg], acc[db][4 * gg + 1],
                              acc[db][4 * gg + 2], acc[db][4 * gg + 3] };
                *reinterpret_cast<float4*>(&olds[(qq * 2 + db) * 1024 + gg * 256 + lane * 4]) = vv;
            }
        if (lane < 32) l_lds[qq * 32 + lane] = lsum;
    }
    __syncthreads();
    if (!kh) {
        float linv = 1.0f / (lsum + l_lds[qq * 32 + ln]);
        for (int db = 0; db < 2; ++db)
            for (int gg = 0; gg < 4; ++gg) {
                float4 vv = *reinterpret_cast<float4*>(
                    &olds[(qq * 2 + db) * 1024 + gg * 256 + lane * 4]);
                acc[db][4 * gg]     += vv.x;
                acc[db][4 * gg + 1] += vv.y;
                acc[db][4 * gg + 2] += vv.z;
                acc[db][4 * gg + 3] += vv.w;
            }
        for (int db = 0; db < 2; ++db)
            for (int reg = 0; reg < 16; ++reg) {
                int qrow = (reg & 3) + 8 * (reg >> 2) + 4 * hk;
                float li = __shfl(linv, qrow);   // lane qrow holds q=qq*32+qrow
                int q = q0 + qq * 32 + qrow;
                out[(size_t)(b * SEQ + q) * 768 + h * 64 + db * 32 + ln] =
                    f2bf(acc[db][reg] * li);
            }
    }
}

extern "C" void kernel_launch(void* const* d_in, const int* in_sizes, int n_in,
                              void* d_out, int out_size, void* d_ws, size_t ws_size,
                              hipStream_t stream) {
    const float* x      = (const float*)d_in[0];
    const float* w_qkv  = (const float*)d_in[1];
    const float* b_qkv  = (const float*)d_in[2];
    const float* w_proj = (const float*)d_in[3];
    const float* b_proj = (const float*)d_in[4];
    float* out = (float*)d_out;
    char* ws = (char*)d_ws;
    // workspace layout (bytes); xbf aliases aout (disjoint lifetimes)
    unsigned short* qkv    = (unsigned short*)(ws);                 // 37748736
    unsigned short* vt_buf = (unsigned short*)(ws + 37748736);      // 12582912
    unsigned short* aout   = (unsigned short*)(ws + 50331648);      // 12582912
    unsigned short* xbf    = aout;                                  // alias: dead before attn writes aout
    unsigned short* wqkvT  = (unsigned short*)(ws + 62914560);      // 3538944
    unsigned short* wprojT = (unsigned short*)(ws + 66453504);      // 1179648
    float*          bqkv_s = (float*)(ws + 67633152);               // 9216

    prep_fused<<<PREP_BLOCKS, 256, 0, stream>>>(
        x, xbf, w_qkv, wqkvT, w_proj, wprojT, b_qkv, bqkv_s);
    // gemm0: 256^2 (288 blocks, r12-verified-correct) — bisection arm A
    gemm_bf16_256<0><<<dim3(M_TOK / 256, N_QKV / 256), 512, 0, stream>>>(
        xbf, wqkvT, bqkv_s, qkv, M_TOK, N_QKV, EMBED);
    vtrans<<<dim3(SEQ / 64, HEADS, BATCH), 256, 0, stream>>>(qkv, vt_buf);
    attn_kernel<<<768, 512, 0, stream>>>(qkv, vt_buf, aout);
    // gemm1: 128^2 (384 blocks, r14-verified) — unchanged control
    gemm_bf16<1><<<(M_TOK / 128) * (EMBED / 128), 256, 0, stream>>>(
        aout, wprojT, b_proj, out, M_TOK, EMBED, EMBED);
}

// Round 16
// 233.513 us; speedup vs baseline: 1.1094x; 1.1094x over previous
//
#include <hip/hip_runtime.h>
#include <hip/hip_bf16.h>

#define EMBED 768
#define HEADS 12
#define HD 64
#define BATCH 4
#define SEQ 2048
#define M_TOK (BATCH*SEQ)   // 8192
#define N_QKV (3*EMBED)     // 2304
#define SL2E 0.18033688011112042f   // (1/8) * log2(e)

typedef short bf8 __attribute__((ext_vector_type(8)));
typedef float f4  __attribute__((ext_vector_type(4)));
typedef float f16v __attribute__((ext_vector_type(16)));
typedef unsigned short us8 __attribute__((ext_vector_type(8)));
typedef unsigned int u32x4 __attribute__((ext_vector_type(4)));

static __device__ inline unsigned short f2bf(float f) {
    unsigned int x = __float_as_uint(f);
    unsigned int r = (x + 0x7fffu + ((x >> 16) & 1u)) >> 16;   // RNE
    return (unsigned short)r;
}

// pack two fp32 -> packed bf16x2
static __device__ inline unsigned int pack2bf(float a, float b) {
#if defined(__has_builtin)
#if __has_builtin(__builtin_amdgcn_cvt_pk_bf16_f32)
    auto r = __builtin_amdgcn_cvt_pk_bf16_f32(a, b);
    return __builtin_bit_cast(unsigned int, r);
#else
    unsigned int ua = (__float_as_uint(a) + 0x8000u) >> 16;
    unsigned int ub = (__float_as_uint(b) + 0x8000u) & 0xffff0000u;
    return ua | ub;
#endif
#else
    unsigned int ua = (__float_as_uint(a) + 0x8000u) >> 16;
    unsigned int ub = (__float_as_uint(b) + 0x8000u) & 0xffff0000u;
    return ua | ub;
#endif
}

#define GLD_LDS(gp, lp) __builtin_amdgcn_global_load_lds( \
    (const __attribute__((address_space(1))) void*)(gp),  \
    (__attribute__((address_space(3))) void*)(lp), 16, 0, 0)

// ---------------- fused prep: cvt + 2 transposes + bias scale in ONE launch ----------
// r6-verified. UNCHANGED.
#define CVT_BLOCKS  ((M_TOK * EMBED) / 1024)                 // 6144
#define TQ_BLOCKS   ((N_QKV / 32) * (EMBED / 32))            // 72*24 = 1728
#define TP_BLOCKS   ((EMBED / 32) * (EMBED / 32))            // 24*24 = 576
#define SB_BLOCKS   9
#define PREP_BLOCKS (CVT_BLOCKS + TQ_BLOCKS + TP_BLOCKS + SB_BLOCKS)

static __device__ inline void transpose_tile(const float* __restrict__ in,
                                             unsigned short* __restrict__ out,
                                             int R, int C, float scale, int nlim,
                                             int c0, int r0, int tx, int ty,
                                             float (*tile)[33]) {
    for (int i = 0; i < 32; i += 8)
        tile[ty + i][tx] = in[(size_t)(r0 + ty + i) * C + c0 + tx];
    __syncthreads();
    for (int i = 0; i < 32; i += 8) {
        int orow = c0 + ty + i;
        float s = (orow < nlim) ? scale : 1.0f;
        out[(size_t)orow * R + r0 + tx] = f2bf(tile[tx][ty + i] * s);
    }
}

__global__ __launch_bounds__(256) void prep_fused(
    const float* __restrict__ x,      unsigned short* __restrict__ xbf,
    const float* __restrict__ w_qkv,  unsigned short* __restrict__ wqkvT,
    const float* __restrict__ w_proj, unsigned short* __restrict__ wprojT,
    const float* __restrict__ b_qkv,  float* __restrict__ bqkv_s) {
    __shared__ float tile[32][33];
    int bid = blockIdx.x, tid = threadIdx.x;
    if (bid < CVT_BLOCKS) {
        int i = (bid * 256 + tid) * 4;
        float4 v = *reinterpret_cast<const float4*>(x + i);
        ushort4 o;
        o.x = f2bf(v.x); o.y = f2bf(v.y); o.z = f2bf(v.z); o.w = f2bf(v.w);
        *reinterpret_cast<ushort4*>(xbf + i) = o;
    } else if (bid < CVT_BLOCKS + TQ_BLOCKS) {
        int t = bid - CVT_BLOCKS;
        int bx = t % (N_QKV / 32), by = t / (N_QKV / 32);
        transpose_tile(w_qkv, wqkvT, EMBED, N_QKV, SL2E, 768,
                       bx * 32, by * 32, tid & 31, tid >> 5, tile);
    } else if (bid < CVT_BLOCKS + TQ_BLOCKS + TP_BLOCKS) {
        int t = bid - CVT_BLOCKS - TQ_BLOCKS;
        int bx = t % (EMBED / 32), by = t / (EMBED / 32);
        transpose_tile(w_proj, wprojT, EMBED, EMBED, 1.0f, 0,
                       bx * 32, by * 32, tid & 31, tid >> 5, tile);
    } else {
        int i = (bid - CVT_BLOCKS - TQ_BLOCKS - TP_BLOCKS) * 256 + tid;
        if (i < N_QKV) bqkv_s[i] = b_qkv[i] * (i < 768 ? SL2E : 1.0f);
    }
}

// ---------------- bf16 GEMM: C[M][N] = A[M][K] * BT[N][K]^T + bias ----------------
// FINAL (r11/r14-verified, 233.9-234.7us total). 128^2 tile. Falsified levers,
// each with mechanism: r8 counted-vmcnt depth-2 (null: TLP already covers the
// drain at ~3 blocks/CU); r11 XCD remap (null: L2 panel locality not the
// bound); r12/r15 256^2 tile (regression: 96KB LDS -> 1 block/CU, 2-phase
// barrier loses all co-resident cover; the 655-682 TF 256^2 references need
// 8-phase intra-block overlap to tolerate 1 block/CU). ~320 TF is this
// structure's level at these shapes (m102). Triple-buffer + counted vmcnt(4)
// + raw s_barrier + XCD remap (kept, neutral).
template<int OUT_MODE>  // 0: bf16 out, 1: fp32 out
__global__ __launch_bounds__(256) void gemm_bf16(
    const unsigned short* __restrict__ A,
    const unsigned short* __restrict__ BT,
    const float* __restrict__ bias,
    void* __restrict__ Cout, int M, int N, int K)
{
    const int LDA = 32;  // unpadded: lane-linear global_load_lds dest
    __shared__ unsigned short a_lds[3][128 * 32];
    __shared__ unsigned short b_lds[3][128 * 32];
    int tid  = threadIdx.x;
    int lane = tid & 63, w = tid >> 6;
    int quad = lane >> 4, cc = lane & 15;
    // XCD-aware decomposition of the 1D block id (r11-verified, neutral)
    int id  = blockIdx.x;
    int xcd = id & 7, j = id >> 3;
    int m0 = (xcd * 8 + (j & 7)) * 128;
    int n0 = (j >> 3) * 128;
    int wr = w >> 1, wc = w & 1;
    int mb = wr * 64, nb = wc * 64;
    const unsigned short* Ab = A + (size_t)m0 * K;
    const unsigned short* Bb = BT + (size_t)n0 * K;
    f4 acc[4][4] = {};
    // staging geometry: 512 slots, 2 per thread (128 rows x 4 chunks of 8 halfwords)
    int li0 = tid,       row0 = li0 >> 2, ch0 = li0 & 3;
    int li1 = 256 + tid, row1 = li1 >> 2, ch1 = li1 & 3;
    // prologue: tiles 0 and 1 into bufs 0,1 (4 vmcnt events per tile per wave)
    GLD_LDS(Ab + (size_t)row0 * K + ch0 * 8,      &a_lds[0][li0 * 8]);
    GLD_LDS(Bb + (size_t)row0 * K + ch0 * 8,      &b_lds[0][li0 * 8]);
    GLD_LDS(Ab + (size_t)row1 * K + ch1 * 8,      &a_lds[0][li1 * 8]);
    GLD_LDS(Bb + (size_t)row1 * K + ch1 * 8,      &b_lds[0][li1 * 8]);
    GLD_LDS(Ab + (size_t)row0 * K + 32 + ch0 * 8, &a_lds[1][li0 * 8]);
    GLD_LDS(Bb + (size_t)row0 * K + 32 + ch0 * 8, &b_lds[1][li0 * 8]);
    GLD_LDS(Ab + (size_t)row1 * K + 32 + ch1 * 8, &a_lds[1][li1 * 8]);
    GLD_LDS(Bb + (size_t)row1 * K + 32 + ch1 * 8, &b_lds[1][li1 * 8]);
    int cur = 0;
    for (int k0 = 0; k0 < K; k0 += 32) {
        // wait: oldest tile (cur) landed; tile cur+1's loads stay in flight.
        if (k0 + 32 < K) {
            asm volatile("s_waitcnt vmcnt(4)\n\ts_barrier" ::: "memory");
        } else {
            asm volatile("s_waitcnt vmcnt(0)\n\ts_barrier" ::: "memory");
        }
        int kn = k0 + 64;
        if (kn < K) {   // issue tile i+2 into buf (i+2)%3 == buf (i-1)%3
            int sb = cur + 2; if (sb >= 3) sb -= 3;
            GLD_LDS(Ab + (size_t)row0 * K + kn + ch0 * 8, &a_lds[sb][li0 * 8]);
            GLD_LDS(Bb + (size_t)row0 * K + kn + ch0 * 8, &b_lds[sb][li0 * 8]);
            GLD_LDS(Ab + (size_t)row1 * K + kn + ch1 * 8, &a_lds[sb][li1 * 8]);
            GLD_LDS(Bb + (size_t)row1 * K + kn + ch1 * 8, &b_lds[sb][li1 * 8]);
        }
        bf8 af[4], bfv[4];
        for (int mi = 0; mi < 4; ++mi)
            af[mi] = *reinterpret_cast<const bf8*>(&a_lds[cur][(mb + mi * 16 + cc) * LDA + quad * 8]);
        for (int ni = 0; ni < 4; ++ni)
            bfv[ni] = *reinterpret_cast<const bf8*>(&b_lds[cur][(nb + ni * 16 + cc) * LDA + quad * 8]);
        for (int mi = 0; mi < 4; ++mi)
            for (int ni = 0; ni < 4; ++ni)
                acc[mi][ni] = __builtin_amdgcn_mfma_f32_16x16x32_bf16(af[mi], bfv[ni], acc[mi][ni], 0, 0, 0);
        cur = (cur == 2) ? 0 : cur + 1;
    }
    for (int mi = 0; mi < 4; ++mi)
        for (int ni = 0; ni < 4; ++ni) {
            int gn = n0 + nb + ni * 16 + cc;
            float bv = bias[gn];
            for (int r = 0; r < 4; ++r) {
                int gm = m0 + mb + mi * 16 + quad * 4 + r;
                float v = acc[mi][ni][r] + bv;
                if (OUT_MODE == 0)
                    ((unsigned short*)Cout)[(size_t)gm * N + gn] = f2bf(v);
                else
                    ((float*)Cout)[(size_t)gm * N + gn] = v;
            }
        }
}

// ------- V transpose: qkv[.][1536+h*64+d] -> vt[b][h][d][t], LDS-tiled -------
__global__ __launch_bounds__(256) void vtrans(
    const unsigned short* __restrict__ qkv, unsigned short* __restrict__ vt)
{
    __shared__ unsigned short lds[64 * 72];
    int tid = threadIdx.x;
    int t0 = blockIdx.x * 64, h = blockIdx.y, b = blockIdx.z;
    for (int p = 0; p < 2; ++p) {
        int li = p * 256 + tid, row = li >> 3, col = li & 7;
        *reinterpret_cast<uint4*>(&lds[row * 72 + col * 8]) =
            *reinterpret_cast<const uint4*>(
                qkv + (size_t)(b * SEQ + t0 + row) * 2304 + 1536 + h * 64 + col * 8);
    }
    __syncthreads();
    for (int p = 0; p < 2; ++p) {
        int li = p * 256 + tid, d = li >> 3, tc = li & 7;
        us8 v;
        for (int j = 0; j < 8; ++j) v[j] = lds[(tc * 8 + j) * 72 + d];
        *reinterpret_cast<us8*>(
            vt + ((size_t)(b * HEADS + h) * 64 + d) * SEQ + t0 + tc * 8) = v;
    }
}

// ---------------- flash attention, 32x32x16 MFMA, q x key wave split ----------------
// FINAL (r3-proven, 92.4us band, 557 TF effective at D=64). Ordering: barrier
// -> ds_write staged regs (tile i+1) -> issue global loads (tile i+2) ->
// compute tile i. 1 barrier/tile (dbuf); in-register P (cvt_pk +
// v_permlane32_swap, 0 bank conflicts). No setprio (lockstep regime).
// r13's ones-trick falsified: lsum dual-issues free under MFMA latency;
// +2 MFMA/step serializes on the matrix pipe (92.8 -> 95.1).
__global__ __launch_bounds__(512, 4) void attn_kernel(
    const unsigned short* __restrict__ qkv,  // [B*T][2304] bf16 (q pre-scaled)
    const unsigned short* __restrict__ vt,   // [B][H][64][T] bf16
    unsigned short* __restrict__ out)        // [B*T][768] bf16
{
    const int LDK = 72;  // 64 + 8 pad
    __shared__ unsigned short smem[18432];   // 36864 B total
    unsigned short* k0b = smem;              // buf0 K [64][72]
    unsigned short* v0b = smem + 4608;       // buf0 V
    unsigned short* k1b = smem + 9216;       // buf1 K
    unsigned short* v1b = smem + 13824;      // buf1 V
    int tid  = threadIdx.x;
    int lane = tid & 63, w = tid >> 6;       // w = 0..7
    int ln   = lane & 31, hk = lane >> 5;    // n-index / k-half within frag
    int qq   = w >> 1, kh = w & 1;           // q-quarter, key-half
    // swizzle: all 16 q-tiles of one (b,h) share id%8 -> same XCD L2
    int id  = blockIdx.x;
    int sub = id >> 3, rem = id & 7;
    int g   = (sub >> 4) * 8 + rem;          // 0..47
    int qt  = sub & 15;
    int b   = g / HEADS, h = g % HEADS;
    int q0  = qt * 128;

    // Q resident as 32x32 B-fragments: B[n=ln -> q][k=kb*16+hk*8+j]
    bf8 qf[4];
    {
        const unsigned short* qp =
            qkv + (size_t)(b * SEQ + q0 + qq * 32 + ln) * 2304 + h * 64 + hk * 8;
        qf[0] = *reinterpret_cast<const bf8*>(qp);
        qf[1] = *reinterpret_cast<const bf8*>(qp + 16);
        qf[2] = *reinterpret_cast<const bf8*>(qp + 32);
        qf[3] = *reinterpret_cast<const bf8*>(qp + 48);
    }
    f16v acc[2] = {};            // [db=d/32]; C: col d = db*32+ln, row q = (reg&3)+8*(reg>>2)+4*hk
    float lsum = 0.f;
    const unsigned short* kbase = qkv + (size_t)b * SEQ * 2304 + 768 + h * 64;
    const unsigned short* vbase = vt + (size_t)(b * HEADS + h) * 64 * SEQ;

    // staging: 512 threads cover 64 rows x 8 chunks once each for K and V
    int srow = tid >> 3, scol = tid & 7;
    const unsigned short* kp = kbase + (size_t)srow * 2304 + scol * 8;
    const unsigned short* vp = vbase + (size_t)srow * SEQ + scol * 8;
    int soff = srow * LDK + scol * 8;

    // prologue: stage tile 0 directly, then prefetch tile 1 into registers
    uint4 kr = *reinterpret_cast<const uint4*>(kp);
    uint4 vr = *reinterpret_cast<const uint4*>(vp);
    *reinterpret_cast<uint4*>(k0b + soff) = kr;
    *reinterpret_cast<uint4*>(v0b + soff) = vr;
    kr = *reinterpret_cast<const uint4*>(kp + (size_t)64 * 2304);
    vr = *reinterpret_cast<const uint4*>(vp + 64);

    const int krow  = (kh * 32 + ln) * LDK + hk * 8;        // K frag base
    const int vrow0 = ln * LDK + kh * 32 + hk * 8;          // V frag base db=0
    const int vrow1 = (32 + ln) * LDK + kh * 32 + hk * 8;   // V frag base db=1

    auto step = [&](const unsigned short* kc, const unsigned short* vc,
                    unsigned short* ko, unsigned short* vo, int kt) {
        __syncthreads();   // buf(kc,vc) visible; prior readers of (ko,vo) drained;
                           // outstanding loads are 1 full phase old -> drain ~free
        // stage tile kt+64 into the other buffer NOW, then issue kt+128 loads:
        // the loads get the whole compute phase below to land before next barrier.
        if (kt + 64 < SEQ) {
            *reinterpret_cast<uint4*>(ko + soff) = kr;
            *reinterpret_cast<uint4*>(vo + soff) = vr;
            if (kt + 128 < SEQ) {
                kr = *reinterpret_cast<const uint4*>(kp + (size_t)(kt + 128) * 2304);
                vr = *reinterpret_cast<const uint4*>(vp + (kt + 128));
            }
        }
        // S^T = K·Q^T over this wave's 32-key half. C: row=key, col=q
        bf8 a0 = *reinterpret_cast<const bf8*>(&kc[krow]);
        bf8 a1 = *reinterpret_cast<const bf8*>(&kc[krow + 16]);
        bf8 a2 = *reinterpret_cast<const bf8*>(&kc[krow + 32]);
        bf8 a3 = *reinterpret_cast<const bf8*>(&kc[krow + 48]);
        f16v z = {};
        z = __builtin_amdgcn_mfma_f32_32x32x16_bf16(a0, qf[0], z, 0, 0, 0);
        z = __builtin_amdgcn_mfma_f32_32x32x16_bf16(a1, qf[1], z, 0, 0, 0);
        z = __builtin_amdgcn_mfma_f32_32x32x16_bf16(a2, qf[2], z, 0, 0, 0);
        z = __builtin_amdgcn_mfma_f32_32x32x16_bf16(a3, qf[3], z, 0, 0, 0);
        // V frags issued now -> DS latency hides under exp2/pack VALU
        bf8 v00 = *reinterpret_cast<const bf8*>(&vc[vrow0]);
        bf8 v01 = *reinterpret_cast<const bf8*>(&vc[vrow0 + 16]);
        bf8 v10 = *reinterpret_cast<const bf8*>(&vc[vrow1]);
        bf8 v11 = *reinterpret_cast<const bf8*>(&vc[vrow1 + 16]);
        // exp2 + in-register P. z reg r holds key (r&3)+8*(r>>2)+4*hk (+kh*32)
        float e[16];
#pragma unroll
        for (int r = 0; r < 16; ++r) e[r] = exp2f(z[r]);
#pragma unroll
        for (int gg = 0; gg < 4; ++gg)
            lsum += (e[4 * gg] + e[4 * gg + 1]) + (e[4 * gg + 2] + e[4 * gg + 3]);
        unsigned int w0 = pack2bf(e[0],  e[1]),  w1 = pack2bf(e[2],  e[3]);
        unsigned int w2 = pack2bf(e[4],  e[5]),  w3 = pack2bf(e[6],  e[7]);
        unsigned int w4 = pack2bf(e[8],  e[9]),  w5 = pack2bf(e[10], e[11]);
        unsigned int w6 = pack2bf(e[12], e[13]), w7 = pack2bf(e[14], e[15]);
        // v_permlane32_swap: hi-half(op0) <-> lo-half(op1)  (T12 recipe order).
        // After swap(w0,w2): w0 = A-word0 {k0,k1|k8,k9}, w2 = A-word2 {k4,k5|k12,k13}
        asm("v_permlane32_swap_b32 %0, %1" : "+v"(w0), "+v"(w2));
        asm("v_permlane32_swap_b32 %0, %1" : "+v"(w1), "+v"(w3));
        asm("v_permlane32_swap_b32 %0, %1" : "+v"(w4), "+v"(w6));
        asm("v_permlane32_swap_b32 %0, %1" : "+v"(w5), "+v"(w7));
        u32x4 pu0 = {w0, w1, w2, w3};   // A[m=q=ln][k = hk*8 + 0..7]   (keys kh*32+0..15)
        u32x4 pu1 = {w4, w5, w6, w7};   // keys kh*32+16..31
        bf8 pa0 = __builtin_bit_cast(bf8, pu0);
        bf8 pa1 = __builtin_bit_cast(bf8, pu1);
        // O += P·V over this wave's key-half
        acc[0] = __builtin_amdgcn_mfma_f32_32x32x16_bf16(pa0, v00, acc[0], 0, 0, 0);
        acc[0] = __builtin_amdgcn_mfma_f32_32x32x16_bf16(pa1, v01, acc[0], 0, 0, 0);
        acc[1] = __builtin_amdgcn_mfma_f32_32x32x16_bf16(pa0, v10, acc[1], 0, 0, 0);
        acc[1] = __builtin_amdgcn_mfma_f32_32x32x16_bf16(pa1, v11, acc[1], 0, 0, 0);
    };

    for (int kt = 0; kt < SEQ; kt += 128) {
        step(k0b, v0b, k1b, v1b, kt);
        step(k1b, v1b, k0b, v0b, kt + 64);
    }

    // combine the two key-halves (wave pairs w, w^1) through reused LDS
    lsum += __shfl_xor(lsum, 32);   // full key-half sum for q = qq*32+ln
    __syncthreads();                // everyone done with k/v before reuse
    float* olds  = reinterpret_cast<float*>(smem);   // 8192 floats = 32768 B
    float* l_lds = olds + 8192;                      // 128 floats
    if (kh) {
        for (int db = 0; db < 2; ++db)
            for (int gg = 0; gg < 4; ++gg) {
                float4 vv = { acc[db][4 * gg], acc[db][4 * gg + 1],
                              acc[db][4 * gg + 2], acc[db][4 * gg + 3] };
                *reinterpret_cast<float4*>(&olds[(qq * 2 + db) * 1024 + gg * 256 + lane * 4]) = vv;
            }
        if (lane < 32) l_lds[qq * 32 + lane] = lsum;
    }
    __syncthreads();
    if (!kh) {
        float linv = 1.0f / (lsum + l_lds[qq * 32 + ln]);
        for (int db = 0; db < 2; ++db)
            for (int gg = 0; gg < 4; ++gg) {
                float4 vv = *reinterpret_cast<float4*>(
                    &olds[(qq * 2 + db) * 1024 + gg * 256 + lane * 4]);
                acc[db][4 * gg]     += vv.x;
                acc[db][4 * gg + 1] += vv.y;
                acc[db][4 * gg + 2] += vv.z;
                acc[db][4 * gg + 3] += vv.w;
            }
        for (int db = 0; db < 2; ++db)
            for (int reg = 0; reg < 16; ++reg) {
                int qrow = (reg & 3) + 8 * (reg >> 2) + 4 * hk;
                float li = __shfl(linv, qrow);   // lane qrow holds q=qq*32+qrow
                int q = q0 + qq * 32 + qrow;
                out[(size_t)(b * SEQ + q) * 768 + h * 64 + db * 32 + ln] =
                    f2bf(acc[db][reg] * li);
            }
    }
}

extern "C" void kernel_launch(void* const* d_in, const int* in_sizes, int n_in,
                              void* d_out, int out_size, void* d_ws, size_t ws_size,
                              hipStream_t stream) {
    const float* x      = (const float*)d_in[0];
    const float* w_qkv  = (const float*)d_in[1];
    const float* b_qkv  = (const float*)d_in[2];
    const float* w_proj = (const float*)d_in[3];
    const float* b_proj = (const float*)d_in[4];
    float* out = (float*)d_out;
    char* ws = (char*)d_ws;
    // workspace layout (bytes); xbf aliases aout (disjoint lifetimes)
    unsigned short* qkv    = (unsigned short*)(ws);                 // 37748736
    unsigned short* vt_buf = (unsigned short*)(ws + 37748736);      // 12582912
    unsigned short* aout   = (unsigned short*)(ws + 50331648);      // 12582912
    unsigned short* xbf    = aout;                                  // alias: dead before attn writes aout
    unsigned short* wqkvT  = (unsigned short*)(ws + 62914560);      // 3538944
    unsigned short* wprojT = (unsigned short*)(ws + 66453504);      // 1179648
    float*          bqkv_s = (float*)(ws + 67633152);               // 9216

    prep_fused<<<PREP_BLOCKS, 256, 0, stream>>>(
        x, xbf, w_qkv, wqkvT, w_proj, wprojT, b_qkv, bqkv_s);
    // 1D grids: XCD-aware m/n decomposition happens inside the kernel
    gemm_bf16<0><<<(M_TOK / 128) * (N_QKV / 128), 256, 0, stream>>>(
        xbf, wqkvT, bqkv_s, qkv, M_TOK, N_QKV, EMBED);
    vtrans<<<dim3(SEQ / 64, HEADS, BATCH), 256, 0, stream>>>(qkv, vt_buf);
    attn_kernel<<<768, 512, 0, stream>>>(qkv, vt_buf, aout);
    gemm_bf16<1><<<(M_TOK / 128) * (EMBED / 128), 256, 0, stream>>>(
        aout, wprojT, b_proj, out, M_TOK, EMBED, EMBED);
}